// Round 5
// baseline (847.802 us; speedup 1.0000x reference)
//
#include <hip/hip_runtime.h>
#include <stdint.h>

#define D_MODEL 1024
#define H_DIM   4096
#define NE      8
#define NCAP    2560
#define NTOK    8192
#define NPAIR   (NTOK * 2)

typedef __attribute__((ext_vector_type(8))) __bf16 bf16x8;
typedef __attribute__((ext_vector_type(4))) float  f32x4;
typedef __attribute__((ext_vector_type(8))) unsigned short ushort8;

__device__ __forceinline__ unsigned short f2bf(float f) {
  union { float f; unsigned u; } v; v.f = f;
  unsigned r = v.u + 0x7fffu + ((v.u >> 16) & 1u);   // round-to-nearest-even
  return (unsigned short)(r >> 16);
}
__device__ __forceinline__ float bf2f(unsigned short s) {
  union { unsigned u; float f; } v; v.u = ((unsigned)s) << 16;
  return v.f;
}
__device__ __forceinline__ float gelu_tanh(float x) {
  float u = 0.7978845608028654f * (x + 0.044715f * x * x * x);
  float e = __expf(2.0f * u);
  float th = 1.0f - 2.0f / (e + 1.0f);
  return 0.5f * x * (1.0f + th);
}
__device__ __forceinline__ void load_lds16(const void* g, void* l) {
  __builtin_amdgcn_global_load_lds(
      (const __attribute__((address_space(1))) unsigned int*)g,
      (__attribute__((address_space(3))) unsigned int*)l, 16, 0, 0);
}

// ---------------- Router ----------------------------------------------------
__global__ __launch_bounds__(256) void router_kernel(
    const float* __restrict__ x, const float* __restrict__ Wr,
    int* __restrict__ pair_e, float* __restrict__ pair_w) {
  int lane = threadIdx.x & 63;
  int t = blockIdx.x * 4 + (threadIdx.x >> 6);
  float acc[NE];
#pragma unroll
  for (int e = 0; e < NE; ++e) acc[e] = 0.0f;
  const float* xr = x + (size_t)t * D_MODEL;
  for (int d = lane; d < D_MODEL; d += 64) {
    float xv = xr[d];
#pragma unroll
    for (int e = 0; e < NE; ++e) acc[e] = fmaf(xv, Wr[d * NE + e], acc[e]);
  }
#pragma unroll
  for (int off = 32; off > 0; off >>= 1) {
#pragma unroll
    for (int e = 0; e < NE; ++e) acc[e] += __shfl_down(acc[e], off, 64);
  }
  if (lane == 0) {
    int i1 = 0;
#pragma unroll
    for (int e = 1; e < NE; ++e) if (acc[e] > acc[i1]) i1 = e;
    int i2 = (i1 == 0) ? 1 : 0;
#pragma unroll
    for (int e = 0; e < NE; ++e) if (e != i1 && acc[e] > acc[i2]) i2 = e;
    float p2 = expf(acc[i2] - acc[i1]);
    float inv = 1.0f / (1.0f + p2);
    pair_e[t * 2]     = i1;  pair_e[t * 2 + 1] = i2;
    pair_w[t * 2]     = inv;
    pair_w[t * 2 + 1] = p2 * inv;
  }
}

// ------- Slot assignment: parallel pair-ordered cumsum (exact ref order) ----
__global__ __launch_bounds__(1024) void assign_kernel(
    const int* __restrict__ pair_e, int* __restrict__ pair_dest,
    int* __restrict__ counts) {
  __shared__ int wtot[16][NE];
  const int tid = threadIdx.x;
  const int lane = tid & 63, w = tid >> 6;

  int ids[16];
  const int4* pe = (const int4*)(pair_e + tid * 16);
#pragma unroll
  for (int q = 0; q < 4; ++q) {
    int4 v = pe[q];
    ids[q * 4 + 0] = v.x; ids[q * 4 + 1] = v.y;
    ids[q * 4 + 2] = v.z; ids[q * 4 + 3] = v.w;
  }
  int c[NE];
#pragma unroll
  for (int e = 0; e < NE; ++e) c[e] = 0;
#pragma unroll
  for (int j = 0; j < 16; ++j) c[ids[j]]++;

  int incl[NE];
#pragma unroll
  for (int e = 0; e < NE; ++e) incl[e] = c[e];
#pragma unroll
  for (int d = 1; d < 64; d <<= 1) {
#pragma unroll
    for (int e = 0; e < NE; ++e) {
      int u = __shfl_up(incl[e], d, 64);
      if (lane >= d) incl[e] += u;
    }
  }
  if (lane == 63) {
#pragma unroll
    for (int e = 0; e < NE; ++e) wtot[w][e] = incl[e];
  }
  __syncthreads();
  if (tid < NE) {
    int run = 0;
#pragma unroll
    for (int ww = 0; ww < 16; ++ww) {
      int t2 = wtot[ww][tid];
      wtot[ww][tid] = run;
      run += t2;
    }
    counts[tid] = run < NCAP ? run : NCAP;
  }
  __syncthreads();

  int off[NE];
#pragma unroll
  for (int e = 0; e < NE; ++e) off[e] = wtot[w][e] + incl[e] - c[e];
#pragma unroll
  for (int j = 0; j < 16; ++j) {
    int e = ids[j];
    int pos = off[e]++;
    pair_dest[tid * 16 + j] = (pos < NCAP) ? (e * NCAP + pos) : (NE * NCAP);
  }
}

// --------------- Dispatch: gather x rows -> bf16 expert buffer --------------
__global__ __launch_bounds__(64) void dispatch_kernel(
    const float* __restrict__ x, const int* __restrict__ pair_dest,
    unsigned short* __restrict__ Xd) {
  int i = blockIdx.x;
  int dest = pair_dest[i];
  if (dest >= NE * NCAP) return;
  int lane = threadIdx.x;
  int t = i >> 1;
  const float4* xr = (const float4*)(x + (size_t)t * D_MODEL);
  ushort4* dr = (ushort4*)(Xd + (size_t)dest * D_MODEL);
#pragma unroll
  for (int c = 0; c < 4; ++c) {
    float4 v = xr[lane + c * 64];
    ushort4 o;
    o.x = f2bf(v.x); o.y = f2bf(v.y); o.z = f2bf(v.z); o.w = f2bf(v.w);
    dr[lane + c * 64] = o;
  }
}

// ------------- Transpose + f32->bf16 convert: [E][R][C] -> [E][C][R] --------
__global__ __launch_bounds__(256) void transpose_cvt(
    const float* __restrict__ src, unsigned short* __restrict__ dst,
    int R, int C) {
  __shared__ float tile[64][69];   // odd stride: <=2-way bank alias both phases
  int e = blockIdx.z;
  int c0 = blockIdx.x * 64, r0 = blockIdx.y * 64;
  const float* s = src + (size_t)e * R * C + (size_t)r0 * C + c0;
  int tc = (threadIdx.x & 15) * 4;
  int tr = threadIdx.x >> 4;
#pragma unroll
  for (int it = 0; it < 4; ++it) {
    int row = tr + it * 16;
    float4 v = *(const float4*)(s + (size_t)row * C + tc);
    tile[row][tc]     = v.x; tile[row][tc + 1] = v.y;
    tile[row][tc + 2] = v.z; tile[row][tc + 3] = v.w;
  }
  __syncthreads();
  unsigned short* d = dst + (size_t)e * R * C + (size_t)c0 * R + r0;
  int oc  = threadIdx.x >> 3;
  int orr = (threadIdx.x & 7) * 8;
#pragma unroll
  for (int it = 0; it < 2; ++it) {
    int crow = oc + it * 32;
    ushort8 v;
#pragma unroll
    for (int j = 0; j < 8; ++j) v[j] = f2bf(tile[orr + j][crow]);
    *(ushort8*)(d + (size_t)crow * R + orr) = v;
  }
}

// ---------- Unified 256x256 grouped GEMM, 8-phase counted-vmcnt -------------
// m201-style schedule in plain HIP. 512 thr = 8 waves (2Mx4N), wave tile
// 128x64. LDS 128KB: buf{0,1} x (A 32KB | B 32KB), BK=64.
// Iteration = 2 K-tiles (t0 -> buf0, t1 -> buf1), 8 phases.
// RACE FIX (round 4 -> 5): at the two vmcnt phases (p1, p5) the mid-phase
// s_barrier is hoisted ABOVE the ds_reads: vmcnt only confirms the wave's OWN
// loads; other waves' staging of the same tile becomes visible only at the
// next barrier. p1/p5 read the tile they themselves confirm, so their reads
// must follow that barrier (PHASE_FIRST). p2-p4/p6-p8 read a tile confirmed
// in an earlier phase + crossed barrier -> reads-before-barrier stays legal
// (latency hidden under barrier arrival, PHASE_BODY).
// Staging schedule (WAR-safe, last reader finished at a previous barrier):
// p1:Am1(t1) p2:Blo(t1) p3:Bhi(t1) p4:Am0(t0+2) p5:Am1(t0+2) p6:Blo(t0+2)
// p7:Bhi(t0+2) p8:Am0(t1+2). vmcnt(4) after p1/p5 stage: all but the 4
// newest loads landed => consumed tile complete. Last iter: p5 -> vmcnt(0).
__global__ __launch_bounds__(512, 2) void moe_gemm_pipe(
    const unsigned short* __restrict__ Abase,
    const unsigned short* __restrict__ Bbase,
    const float* __restrict__ bias,
    unsigned short* __restrict__ Cout,
    const int* __restrict__ counts,
    int N, int K, int NX, int do_gelu) {
  const int M = NCAP;
  const int KT2 = K >> 7;                  // iterations (2 K-tiles each)
  __shared__ char smem[131072];

  // ---- bijective XCD swizzle (nwg = NX*8, divisible by 8) ----
  int orig = blockIdx.x;
  int q = (NX * NE) >> 3;
  int wgid = (orig & 7) * q + (orig >> 3);
  const int e = wgid / NX;
  int r = wgid % NX;

  int grp = r >> 2, lid = r & 3;           // 2x2 supertile for L2 reuse
  int gm = grp % 5, gn = grp / 5;
  const int m0 = (gm * 2 + (lid & 1)) * 256;
  const int n0 = (gn * 2 + (lid >> 1)) * 256;
  if (m0 >= counts[e]) return;

  const int tid = threadIdx.x;
  const int lane = tid & 63;
  const int wid = tid >> 6;
  const int wm = (wid >> 2) * 128;         // wave M-offset {0,128}
  const int wn = (wid & 3) * 64;           // wave N-offset {0,64,128,192}

  const unsigned short* A = Abase + (size_t)e * M * K;
  const unsigned short* B = Bbase + (size_t)e * N * K;

  f32x4 acc[8][4];
  f32x4 zero = {0.f, 0.f, 0.f, 0.f};
#pragma unroll
  for (int i = 0; i < 8; ++i)
#pragma unroll
    for (int j = 0; j < 4; ++j) acc[i][j] = zero;

  // Per-thread staging source offsets (elements). gload covers 64 rows:
  // row = R + (tid>>3), chunk = (tid&7) ^ ((tid>>3)&7)  (inverse XOR swizzle).
  const size_t soA = (size_t)(m0 + (tid >> 3)) * K + ((tid & 7) ^ ((tid >> 3) & 7)) * 8;
  const size_t soB = (size_t)(n0 + (tid >> 3)) * K + ((tid & 7) ^ ((tid >> 3) & 7)) * 8;
  const int wdst = wid * 1024;             // wave-uniform LDS dest offset

  // ds_read swizzled chunk offsets (lane-only; (ar&7) == (lane&7) since all
  // row-base terms are multiples of 16).
  const int sw0 = (((lane >> 4) + 0) ^ (lane & 7)) * 16;
  const int sw1 = (((lane >> 4) + 4) ^ (lane & 7)) * 16;
  const int abase = wm + (lane & 15);
  const int bbase = wn + (lane & 15);

  // half: 0 -> A rows {0-63,128-191}, 1 -> {64-127,192-255}
#define STAGE_A(tile, half) do {                                           \
    char* _d = smem + ((tile) & 1) * 65536 + (half) * 8192 + wdst;         \
    const unsigned short* _s = A + soA + (size_t)(half) * 64 * K + (tile) * 64; \
    load_lds16(_s, _d);                                                    \
    load_lds16(_s + (size_t)128 * K, _d + 16384);                          \
  } while (0)
  // half: 0 -> B rows 0-127, 1 -> rows 128-255
#define STAGE_B(tile, half) do {                                           \
    char* _d = smem + ((tile) & 1) * 65536 + 32768 + (half) * 16384 + wdst; \
    const unsigned short* _s = B + soB + (size_t)(half) * 128 * K + (tile) * 64; \
    load_lds16(_s, _d);                                                    \
    load_lds16(_s + (size_t)64 * K, _d + 8192);                            \
  } while (0)

#define DS_READS(tile, kk, mh) do {                                        \
    const char* _Ab = smem + ((tile) & 1) * 65536;                         \
    const char* _Bb = _Ab + 32768;                                         \
    _Pragma("unroll")                                                      \
    for (int f = 0; f < 4; ++f)                                            \
      af[f] = *(const bf16x8*)(_Ab + (abase + (mh) * 64 + f * 16) * 128 + sw##kk); \
    if ((mh) == 0) {                                                       \
      _Pragma("unroll")                                                    \
      for (int f = 0; f < 4; ++f)                                          \
        bfr[f] = *(const bf16x8*)(_Bb + (bbase + f * 16) * 128 + sw##kk);  \
    }                                                                      \
  } while (0)

#define MFMA_CLUSTER(mh) do {                                              \
    asm volatile("s_waitcnt lgkmcnt(0)" ::: "memory");                     \
    __builtin_amdgcn_sched_barrier(0);                                     \
    __builtin_amdgcn_s_setprio(1);                                        \
    _Pragma("unroll")                                                      \
    for (int i = 0; i < 4; ++i)                                            \
      _Pragma("unroll")                                                    \
      for (int j = 0; j < 4; ++j)                                          \
        acc[(mh) * 4 + i][j] = __builtin_amdgcn_mfma_f32_16x16x32_bf16(    \
            af[i], bfr[j], acc[(mh) * 4 + i][j], 0, 0, 0);                 \
    __builtin_amdgcn_s_setprio(0);                                        \
    __builtin_amdgcn_s_barrier();                                          \
  } while (0)

  // Normal phase: reads BEFORE barrier (tile confirmed in an earlier phase).
#define PHASE_BODY(tile, kk, mh) do {                                      \
    DS_READS(tile, kk, mh);                                                \
    __builtin_amdgcn_sched_barrier(0);                                     \
    __builtin_amdgcn_s_barrier();                                          \
    MFMA_CLUSTER(mh);                                                      \
  } while (0)

  // vmcnt phase: barrier FIRST (this phase reads the tile it just confirmed;
  // other waves' staging is only visible after the barrier).
#define PHASE_FIRST(tile, kk, mh) do {                                     \
    __builtin_amdgcn_sched_barrier(0);                                     \
    __builtin_amdgcn_s_barrier();                                          \
    __builtin_amdgcn_sched_barrier(0);                                     \
    DS_READS(tile, kk, mh);                                                \
    MFMA_CLUSTER(mh);                                                      \
  } while (0)

  // Prologue: Am0(0) Am1(0) Blo(0) Bhi(0) Am0(1)  (10 gloads, steady order)
  STAGE_A(0, 0); STAGE_A(0, 1); STAGE_B(0, 0); STAGE_B(0, 1); STAGE_A(1, 0);

  for (int it = 0; it < KT2; ++it) {
    const int t0 = 2 * it, t1 = 2 * it + 1;
    const bool notlast = (it < KT2 - 1);
    bf16x8 af[4], bfr[4];
    // p1: (t0,k0,m0)
    STAGE_A(t1, 1);
    asm volatile("s_waitcnt vmcnt(4)" ::: "memory");
    PHASE_FIRST(t0, 0, 0);
    // p2: (t0,k0,m1)
    STAGE_B(t1, 0);
    PHASE_BODY(t0, 0, 1);
    // p3: (t0,k1,m0)
    STAGE_B(t1, 1);
    PHASE_BODY(t0, 1, 0);
    // p4: (t0,k1,m1)
    if (notlast) STAGE_A(t0 + 2, 0);
    PHASE_BODY(t0, 1, 1);
    // p5: (t1,k0,m0)
    if (notlast) {
      STAGE_A(t0 + 2, 1);
      asm volatile("s_waitcnt vmcnt(4)" ::: "memory");
    } else {
      asm volatile("s_waitcnt vmcnt(0)" ::: "memory");
    }
    PHASE_FIRST(t1, 0, 0);
    // p6: (t1,k0,m1)
    if (notlast) STAGE_B(t0 + 2, 0);
    PHASE_BODY(t1, 0, 1);
    // p7: (t1,k1,m0)
    if (notlast) STAGE_B(t0 + 2, 1);
    PHASE_BODY(t1, 1, 0);
    // p8: (t1,k1,m1)
    if (notlast) STAGE_A(t1 + 2, 0);
    PHASE_BODY(t1, 1, 1);
  }
#undef STAGE_A
#undef STAGE_B
#undef DS_READS
#undef MFMA_CLUSTER
#undef PHASE_BODY
#undef PHASE_FIRST

  // ---- Epilogue: bias(+gelu), bf16 C tile (256x256 = 128KB) in LDS --------
  // (p8's trailing s_barrier ordered all LDS reads before these writes; the
  //  last iteration issues no stages after its vmcnt(0), so no gload in
  //  flight can land into smem here.)
  const float* be = bias + (size_t)e * N;
#pragma unroll
  for (int i = 0; i < 8; ++i) {
    int rbase = wm + (i & 3) * 16 + (i >> 2) * 64 + ((lane >> 4) << 2);
#pragma unroll
    for (int j = 0; j < 4; ++j) {
      int col = wn + j * 16 + (lane & 15);
      float bv = be[n0 + col];
#pragma unroll
      for (int r2 = 0; r2 < 4; ++r2) {
        float xv = acc[i][j][r2] + bv;
        if (do_gelu) xv = gelu_tanh(xv);
        *(unsigned short*)(smem + (size_t)(rbase + r2) * 512 + col * 2) = f2bf(xv);
      }
    }
  }
  __syncthreads();
#pragma unroll
  for (int it = 0; it < 16; ++it) {
    int idx = it * 4096 + tid * 8;
    int row = idx >> 8, col = idx & 255;
    ushort8 v = *(const ushort8*)(smem + (size_t)idx * 2);
    *(ushort8*)(Cout + ((size_t)e * M + m0 + row) * N + n0 + col) = v;
  }
}

// --------------- Combine: y[t] = sum_k w_k * Ebuf[dest_k] -------------------
__global__ __launch_bounds__(256) void combine_kernel(
    const unsigned short* __restrict__ Ebuf,
    const int* __restrict__ pair_dest,
    const float* __restrict__ pair_w,
    float* __restrict__ out) {
  int t = blockIdx.x;
  int d0 = threadIdx.x * 4;
  float4 r = {0.f, 0.f, 0.f, 0.f};
#pragma unroll
  for (int k = 0; k < 2; ++k) {
    int dest = pair_dest[t * 2 + k];
    if (dest < NE * NCAP) {
      float w = pair_w[t * 2 + k];
      ushort4 v = *(const ushort4*)(Ebuf + (size_t)dest * D_MODEL + d0);
      r.x += w * bf2f(v.x); r.y += w * bf2f(v.y);
      r.z += w * bf2f(v.z); r.w += w * bf2f(v.w);
    }
  }
  *(float4*)(out + (size_t)t * D_MODEL + d0) = r;
}

// ---------------------------------------------------------------------------
extern "C" void kernel_launch(void* const* d_in, const int* in_sizes, int n_in,
                              void* d_out, int out_size, void* d_ws, size_t ws_size,
                              hipStream_t stream) {
  const float* x  = (const float*)d_in[0];
  const float* Wr = (const float*)d_in[1];
  const float* W1 = (const float*)d_in[2];
  const float* b1 = (const float*)d_in[3];
  const float* W2 = (const float*)d_in[4];
  const float* b2 = (const float*)d_in[5];
  float* out = (float*)d_out;

  char* ws = (char*)d_ws;
  unsigned short* W1T  = (unsigned short*)(ws + 0);            // 64 MB
  unsigned short* W2T  = (unsigned short*)(ws + 67108864);     // 64 MB
  unsigned short* Xd   = (unsigned short*)(ws + 134217728);    // 40 MB
  unsigned short* Ebuf = Xd;   // aliased: Xd dead after GEMM1
  unsigned short* Hbuf = (unsigned short*)(ws + 176160768);    // 160 MB
  int*   pair_e    = (int*)(ws + 343932928);
  float* pair_w    = (float*)(ws + 343998464);
  int*   pair_dest = (int*)(ws + 344064000);
  int*   counts    = (int*)(ws + 344129536);

  // W1 [E][D][H] -> W1T [E][H][D]; W2 [E][H][D] -> W2T [E][D][H]
  transpose_cvt<<<dim3(H_DIM / 64, D_MODEL / 64, NE), 256, 0, stream>>>(W1, W1T, D_MODEL, H_DIM);
  transpose_cvt<<<dim3(D_MODEL / 64, H_DIM / 64, NE), 256, 0, stream>>>(W2, W2T, H_DIM, D_MODEL);

  router_kernel<<<NTOK / 4, 256, 0, stream>>>(x, Wr, pair_e, pair_w);
  assign_kernel<<<1, 1024, 0, stream>>>(pair_e, pair_dest, counts);
  dispatch_kernel<<<NPAIR, 64, 0, stream>>>(x, pair_dest, Xd);

  // GEMM1: h = gelu(Xd @ W1 + b1)   M=CAP N=H K=D
  {
    int nx = (NCAP / 256) * (H_DIM / 256);   // 160
    moe_gemm_pipe<<<nx * NE, 512, 0, stream>>>(
        Xd, W1T, b1, Hbuf, counts, H_DIM, D_MODEL, nx, 1);
  }
  // GEMM2: Ebuf = h @ W2 + b2       M=CAP N=D K=H
  {
    int nx = (NCAP / 256) * (D_MODEL / 256); // 40
    moe_gemm_pipe<<<nx * NE, 512, 0, stream>>>(
        Hbuf, W2T, b2, Ebuf, counts, D_MODEL, H_DIM, nx, 0);
  }

  combine_kernel<<<NTOK, 256, 0, stream>>>(Ebuf, pair_dest, pair_w, out);
}

// Round 6
// 716.715 us; speedup vs baseline: 1.1829x; 1.1829x over previous
//
#include <hip/hip_runtime.h>
#include <stdint.h>

#define D_MODEL 1024
#define H_DIM   4096
#define NE      8
#define NCAP    2560
#define NTOK    8192
#define NPAIR   (NTOK * 2)

typedef __attribute__((ext_vector_type(8))) __bf16 bf16x8;
typedef __attribute__((ext_vector_type(4))) float  f32x4;
typedef __attribute__((ext_vector_type(8))) unsigned short ushort8;

__device__ __forceinline__ unsigned short f2bf(float f) {
  union { float f; unsigned u; } v; v.f = f;
  unsigned r = v.u + 0x7fffu + ((v.u >> 16) & 1u);   // round-to-nearest-even
  return (unsigned short)(r >> 16);
}
__device__ __forceinline__ float bf2f(unsigned short s) {
  union { unsigned u; float f; } v; v.u = ((unsigned)s) << 16;
  return v.f;
}
__device__ __forceinline__ float gelu_tanh(float x) {
  float u = 0.7978845608028654f * (x + 0.044715f * x * x * x);
  float e = __expf(2.0f * u);
  float th = 1.0f - 2.0f / (e + 1.0f);
  return 0.5f * x * (1.0f + th);
}
__device__ __forceinline__ void load_lds16(const void* g, void* l) {
  __builtin_amdgcn_global_load_lds(
      (const __attribute__((address_space(1))) unsigned int*)g,
      (__attribute__((address_space(3))) unsigned int*)l, 16, 0, 0);
}

// ---------------- Router ----------------------------------------------------
__global__ __launch_bounds__(256) void router_kernel(
    const float* __restrict__ x, const float* __restrict__ Wr,
    int* __restrict__ pair_e, float* __restrict__ pair_w) {
  int lane = threadIdx.x & 63;
  int t = blockIdx.x * 4 + (threadIdx.x >> 6);
  float acc[NE];
#pragma unroll
  for (int e = 0; e < NE; ++e) acc[e] = 0.0f;
  const float* xr = x + (size_t)t * D_MODEL;
  for (int d = lane; d < D_MODEL; d += 64) {
    float xv = xr[d];
#pragma unroll
    for (int e = 0; e < NE; ++e) acc[e] = fmaf(xv, Wr[d * NE + e], acc[e]);
  }
#pragma unroll
  for (int off = 32; off > 0; off >>= 1) {
#pragma unroll
    for (int e = 0; e < NE; ++e) acc[e] += __shfl_down(acc[e], off, 64);
  }
  if (lane == 0) {
    int i1 = 0;
#pragma unroll
    for (int e = 1; e < NE; ++e) if (acc[e] > acc[i1]) i1 = e;
    int i2 = (i1 == 0) ? 1 : 0;
#pragma unroll
    for (int e = 0; e < NE; ++e) if (e != i1 && acc[e] > acc[i2]) i2 = e;
    float p2 = expf(acc[i2] - acc[i1]);
    float inv = 1.0f / (1.0f + p2);
    pair_e[t * 2]     = i1;  pair_e[t * 2 + 1] = i2;
    pair_w[t * 2]     = inv;
    pair_w[t * 2 + 1] = p2 * inv;
  }
}

// ------- Slot assignment: parallel pair-ordered cumsum (exact ref order) ----
__global__ __launch_bounds__(1024) void assign_kernel(
    const int* __restrict__ pair_e, int* __restrict__ pair_dest,
    int* __restrict__ counts) {
  __shared__ int wtot[16][NE];
  const int tid = threadIdx.x;
  const int lane = tid & 63, w = tid >> 6;

  int ids[16];
  const int4* pe = (const int4*)(pair_e + tid * 16);
#pragma unroll
  for (int q = 0; q < 4; ++q) {
    int4 v = pe[q];
    ids[q * 4 + 0] = v.x; ids[q * 4 + 1] = v.y;
    ids[q * 4 + 2] = v.z; ids[q * 4 + 3] = v.w;
  }
  int c[NE];
#pragma unroll
  for (int e = 0; e < NE; ++e) c[e] = 0;
#pragma unroll
  for (int j = 0; j < 16; ++j) c[ids[j]]++;

  int incl[NE];
#pragma unroll
  for (int e = 0; e < NE; ++e) incl[e] = c[e];
#pragma unroll
  for (int d = 1; d < 64; d <<= 1) {
#pragma unroll
    for (int e = 0; e < NE; ++e) {
      int u = __shfl_up(incl[e], d, 64);
      if (lane >= d) incl[e] += u;
    }
  }
  if (lane == 63) {
#pragma unroll
    for (int e = 0; e < NE; ++e) wtot[w][e] = incl[e];
  }
  __syncthreads();
  if (tid < NE) {
    int run = 0;
#pragma unroll
    for (int ww = 0; ww < 16; ++ww) {
      int t2 = wtot[ww][tid];
      wtot[ww][tid] = run;
      run += t2;
    }
    counts[tid] = run < NCAP ? run : NCAP;
  }
  __syncthreads();

  int off[NE];
#pragma unroll
  for (int e = 0; e < NE; ++e) off[e] = wtot[w][e] + incl[e] - c[e];
#pragma unroll
  for (int j = 0; j < 16; ++j) {
    int e = ids[j];
    int pos = off[e]++;
    pair_dest[tid * 16 + j] = (pos < NCAP) ? (e * NCAP + pos) : (NE * NCAP);
  }
}

// --------- Dispatch (by token): gather x rows -> bf16 expert buffer ---------
// One block per token: load+convert the row ONCE, store to both expert slots.
__global__ __launch_bounds__(64) void dispatch_kernel(
    const float* __restrict__ x, const int* __restrict__ pair_dest,
    unsigned short* __restrict__ Xd) {
  int t = blockIdx.x;
  int d0 = pair_dest[t * 2], d1 = pair_dest[t * 2 + 1];
  bool k0 = d0 < NE * NCAP, k1 = d1 < NE * NCAP;
  if (!k0 && !k1) return;
  int lane = threadIdx.x;
  const float4* xr = (const float4*)(x + (size_t)t * D_MODEL);
  ushort4* r0 = (ushort4*)(Xd + (size_t)d0 * D_MODEL);
  ushort4* r1 = (ushort4*)(Xd + (size_t)d1 * D_MODEL);
#pragma unroll
  for (int c = 0; c < 4; ++c) {
    float4 v = xr[lane + c * 64];
    ushort4 o;
    o.x = f2bf(v.x); o.y = f2bf(v.y); o.z = f2bf(v.z); o.w = f2bf(v.w);
    if (k0) r0[lane + c * 64] = o;
    if (k1) r1[lane + c * 64] = o;
  }
}

// ------------- Transpose + f32->bf16 convert: [E][R][C] -> [E][C][R] --------
__global__ __launch_bounds__(256) void transpose_cvt(
    const float* __restrict__ src, unsigned short* __restrict__ dst,
    int R, int C) {
  __shared__ float tile[64][69];   // odd stride: <=2-way bank alias both phases
  int e = blockIdx.z;
  int c0 = blockIdx.x * 64, r0 = blockIdx.y * 64;
  const float* s = src + (size_t)e * R * C + (size_t)r0 * C + c0;
  int tc = (threadIdx.x & 15) * 4;
  int tr = threadIdx.x >> 4;
#pragma unroll
  for (int it = 0; it < 4; ++it) {
    int row = tr + it * 16;
    float4 v = *(const float4*)(s + (size_t)row * C + tc);
    tile[row][tc]     = v.x; tile[row][tc + 1] = v.y;
    tile[row][tc + 2] = v.z; tile[row][tc + 3] = v.w;
  }
  __syncthreads();
  unsigned short* d = dst + (size_t)e * R * C + (size_t)c0 * R + r0;
  int oc  = threadIdx.x >> 3;
  int orr = (threadIdx.x & 7) * 8;
#pragma unroll
  for (int it = 0; it < 2; ++it) {
    int crow = oc + it * 32;
    ushort8 v;
#pragma unroll
    for (int j = 0; j < 8; ++j) v[j] = f2bf(tile[orr + j][crow]);
    *(ushort8*)(d + (size_t)crow * R + orr) = v;
  }
}

// --------------------------- Grouped MFMA GEMM (128^2) ----------------------
// Proven round-0 structure (5 blocks/CU TLP, single 32KB LDS buffer) + 1-D
// grid with bijective XCD swizzle: grid = nxpe*8; orig&7 = XCD = expert, so
// each expert's B panel is fetched/served by a single XCD's L2.
__global__ __launch_bounds__(256, 4) void moe_gemm(
    const unsigned short* __restrict__ Abase,
    const unsigned short* __restrict__ Bbase,
    const float* __restrict__ bias,
    unsigned short* __restrict__ Cout,
    const int* __restrict__ counts,
    int M, int N, int K, int NBM, int nxpe, int do_gelu) {
  __shared__ char smem[32768];          // As 16KB | Bs 16KB; reused for C tile
  int orig = blockIdx.x;
  const int e = orig & 7;               // XCD-resident expert
  int r = orig >> 3;                    // block index within expert [0,nxpe)
  int grp = r >> 4, lid = r & 15;
  int mg = NBM >> 2;
  int gm = grp % mg, gn = grp / mg;
  const int m0 = (gm * 4 + (lid & 3)) * 128;
  const int n0 = (gn * 4 + (lid >> 2)) * 128;
  const int cnt = counts[e];
  if (m0 >= cnt) return;

  const int tid = threadIdx.x;
  const int lane = tid & 63;
  const int wid = tid >> 6;
  const int wm = (wid & 1) * 64;
  const int wn = (wid >> 1) * 64;

  const unsigned short* A = Abase + (size_t)e * M * K;
  const unsigned short* B = Bbase + (size_t)e * N * K;

  f32x4 acc[4][4];
  f32x4 zero = {0.f, 0.f, 0.f, 0.f};
#pragma unroll
  for (int i = 0; i < 4; ++i)
#pragma unroll
    for (int j = 0; j < 4; ++j) acc[i][j] = zero;

  char* As = smem;
  char* Bs = smem + 16384;

  const unsigned short* ga[4];
  const unsigned short* gb[4];
  int ldso[4];
#pragma unroll
  for (int c = 0; c < 4; ++c) {
    int ci = c * 256 + wid * 64 + lane;
    int srow = ci >> 3;
    int sgc = (ci & 7) ^ (srow & 7);    // XOR swizzle on global chunk
    ga[c] = A + (size_t)(m0 + srow) * K + sgc * 8;
    gb[c] = B + (size_t)(n0 + srow) * K + sgc * 8;
    ldso[c] = (c * 256 + wid * 64) * 16;
  }

  const int KT = K >> 6;
  for (int kt = 0; kt < KT; ++kt) {
#pragma unroll
    for (int c = 0; c < 4; ++c) {
      load_lds16(ga[c], As + ldso[c]);
      ga[c] += 64;
      load_lds16(gb[c], Bs + ldso[c]);
      gb[c] += 64;
    }
    __syncthreads();
#pragma unroll
    for (int kk = 0; kk < 2; ++kk) {
      bf16x8 af[4], bfr[4];
      int lc = kk * 4 + (lane >> 4);
#pragma unroll
      for (int f = 0; f < 4; ++f) {
        int ar = wm + f * 16 + (lane & 15);
        af[f] = *(const bf16x8*)(As + ar * 128 + ((lc ^ (ar & 7)) * 16));
        int br = wn + f * 16 + (lane & 15);
        bfr[f] = *(const bf16x8*)(Bs + br * 128 + ((lc ^ (br & 7)) * 16));
      }
#pragma unroll
      for (int i = 0; i < 4; ++i)
#pragma unroll
        for (int j = 0; j < 4; ++j)
          acc[i][j] = __builtin_amdgcn_mfma_f32_16x16x32_bf16(
              af[i], bfr[j], acc[i][j], 0, 0, 0);
    }
    __syncthreads();
  }

  // ---- Epilogue: stage bf16 C tile in LDS, coalesced store ----------------
  const float* be = bias + (size_t)e * N;
#pragma unroll
  for (int i = 0; i < 4; ++i) {
    int rbase = wm + i * 16 + (lane >> 4) * 4;
#pragma unroll
    for (int j = 0; j < 4; ++j) {
      int col = wn + j * 16 + (lane & 15);
      float bv = be[n0 + col];
#pragma unroll
      for (int r2 = 0; r2 < 4; ++r2) {
        float xv = acc[i][j][r2] + bv;
        if (do_gelu) xv = gelu_tanh(xv);
        *(unsigned short*)(smem + (rbase + r2) * 256 + col * 2) = f2bf(xv);
      }
    }
  }
  __syncthreads();
  const int r16 = tid >> 4, c16 = tid & 15;
#pragma unroll
  for (int it = 0; it < 8; ++it) {
    int row = it * 16 + r16;
    ushort8 v = *(const ushort8*)(smem + row * 256 + c16 * 16);
    *(ushort8*)(Cout + ((size_t)e * M + m0 + row) * N + n0 + c16 * 8) = v;
  }
}

// --------------- Combine: y[t] = sum_k w_k * Ebuf[dest_k] -------------------
__global__ __launch_bounds__(256) void combine_kernel(
    const unsigned short* __restrict__ Ebuf,
    const int* __restrict__ pair_dest,
    const float* __restrict__ pair_w,
    float* __restrict__ out) {
  int t = blockIdx.x;
  int d0 = threadIdx.x * 4;
  float4 r = {0.f, 0.f, 0.f, 0.f};
#pragma unroll
  for (int k = 0; k < 2; ++k) {
    int dest = pair_dest[t * 2 + k];
    if (dest < NE * NCAP) {
      float w = pair_w[t * 2 + k];
      ushort4 v = *(const ushort4*)(Ebuf + (size_t)dest * D_MODEL + d0);
      r.x += w * bf2f(v.x); r.y += w * bf2f(v.y);
      r.z += w * bf2f(v.z); r.w += w * bf2f(v.w);
    }
  }
  *(float4*)(out + (size_t)t * D_MODEL + d0) = r;
}

// ---------------------------------------------------------------------------
extern "C" void kernel_launch(void* const* d_in, const int* in_sizes, int n_in,
                              void* d_out, int out_size, void* d_ws, size_t ws_size,
                              hipStream_t stream) {
  const float* x  = (const float*)d_in[0];
  const float* Wr = (const float*)d_in[1];
  const float* W1 = (const float*)d_in[2];
  const float* b1 = (const float*)d_in[3];
  const float* W2 = (const float*)d_in[4];
  const float* b2 = (const float*)d_in[5];
  float* out = (float*)d_out;

  char* ws = (char*)d_ws;
  unsigned short* W1T  = (unsigned short*)(ws + 0);            // 64 MB
  unsigned short* W2T  = (unsigned short*)(ws + 67108864);     // 64 MB
  unsigned short* Xd   = (unsigned short*)(ws + 134217728);    // 40 MB
  unsigned short* Ebuf = Xd;   // aliased: Xd dead after GEMM1
  unsigned short* Hbuf = (unsigned short*)(ws + 176160768);    // 160 MB
  int*   pair_e    = (int*)(ws + 343932928);
  float* pair_w    = (float*)(ws + 343998464);
  int*   pair_dest = (int*)(ws + 344064000);
  int*   counts    = (int*)(ws + 344129536);

  // W1 [E][D][H] -> W1T [E][H][D]; W2 [E][H][D] -> W2T [E][D][H]
  transpose_cvt<<<dim3(H_DIM / 64, D_MODEL / 64, NE), 256, 0, stream>>>(W1, W1T, D_MODEL, H_DIM);
  transpose_cvt<<<dim3(D_MODEL / 64, H_DIM / 64, NE), 256, 0, stream>>>(W2, W2T, H_DIM, D_MODEL);

  router_kernel<<<NTOK / 4, 256, 0, stream>>>(x, Wr, pair_e, pair_w);
  assign_kernel<<<1, 1024, 0, stream>>>(pair_e, pair_dest, counts);
  dispatch_kernel<<<NTOK, 64, 0, stream>>>(x, pair_dest, Xd);

  // GEMM1: h = gelu(Xd @ W1 + b1)   M=CAP N=H K=D
  {
    int nxpe = (NCAP / 128) * (H_DIM / 128);   // 640 blocks/expert
    moe_gemm<<<nxpe * NE, 256, 0, stream>>>(
        Xd, W1T, b1, Hbuf, counts, NCAP, H_DIM, D_MODEL, NCAP / 128, nxpe, 1);
  }
  // GEMM2: Ebuf = h @ W2 + b2       M=CAP N=D K=H
  {
    int nxpe = (NCAP / 128) * (D_MODEL / 128); // 160 blocks/expert
    moe_gemm<<<nxpe * NE, 256, 0, stream>>>(
        Hbuf, W2T, b2, Ebuf, counts, NCAP, D_MODEL, H_DIM, NCAP / 128, nxpe, 0);
  }

  combine_kernel<<<NTOK, 256, 0, stream>>>(Ebuf, pair_dest, pair_w, out);
}